// Round 4
// baseline (194.652 us; speedup 1.0000x reference)
//
#include <hip/hip_runtime.h>

// out[m,u] = x2[m] + w2[u] - 2 * sum_k x[m,k] * w[k,u]
// x[8*4096, 128] f32, w[128, 1024] f32, out[32768, 1024] f32
#define M_TOT 32768
#define K_DIM 128
#define U_TOT 1024

typedef short s16x8 __attribute__((ext_vector_type(8)));   // 8 bf16 as shorts
typedef float f32x4 __attribute__((ext_vector_type(4)));

// round-to-nearest-even fp32 -> bf16 (as ushort)
__device__ inline unsigned int f2bf(float f) {
    union { float f; unsigned int u; } v; v.f = f;
    unsigned int r = v.u + 0x7FFFu + ((v.u >> 16) & 1u);
    return r >> 16;
}

// Tiny prep: w[128,1024] -> w^T bf16 (u-major rows, k contiguous) + w2[u].
// One wave per u column; 256 blocks. ~0.5 MiB read, 260 KiB written.
__global__ __launch_bounds__(256) void prep_w(
    const float* __restrict__ w, unsigned int* __restrict__ wt, float* __restrict__ w2)
{
    const int lane = threadIdx.x & 63;
    const int u = (blockIdx.x << 2) + (threadIdx.x >> 6);
    const float a = w[(size_t)(2 * lane) * U_TOT + u];
    const float b = w[(size_t)(2 * lane + 1) * U_TOT + u];
    float s = a * a + b * b;
    #pragma unroll
    for (int off = 32; off; off >>= 1) s += __shfl_xor(s, off);
    wt[u * 64 + lane] = f2bf(a) | (f2bf(b) << 16);
    if (lane == 0) w2[u] = s;
}

// LDS-free GEMM, x read as fp32 directly from global (in-register bf16 cvt),
// x2 computed from the same registers via cross-quad shuffles.
// 128x128 tile per block (4 waves, 2x2 of 64x64); transposed MFMA accumulate
// (D row = u) so the epilogue stores float4 along u.
// Grid: 256 m-tiles * 8 u-tiles = 2048 blocks of 256 threads.
__global__ __launch_bounds__(256) void gemm_kernel(
    const float* __restrict__ x, const unsigned short* __restrict__ wt,
    const float* __restrict__ w2, float* __restrict__ out)
{
    const int tid = threadIdx.x;
    const int wv = tid >> 6;
    const int lane = tid & 63;
    const int col = lane & 15;
    const int quad = lane >> 4;
    const int m0 = (int)(blockIdx.x >> 3) * 128;
    const int u0 = (int)(blockIdx.x & 7) * 128;
    const int wm = (wv & 1) * 64;
    const int wn = (wv >> 1) * 64;

    // Lane's A source: fp32 row m, this quad's k-slice. B source: bf16 w^T row u.
    const float* xrow = x + (size_t)(m0 + wm + col) * K_DIM + quad * 8;
    const unsigned short* brow = wt + (size_t)(u0 + wn + col) * K_DIM + quad * 8;

    f32x4 acc[4][4] = {};         // acc[a][b]: m-subtile a, u-subtile b
    float x2p[4] = {0.f, 0.f, 0.f, 0.f};

    #pragma unroll 1
    for (int kc = 0; kc < 4; ++kc) {
        s16x8 af[4], bf[4];
        #pragma unroll
        for (int t = 0; t < 4; ++t) {
            const float* ap = xrow + (size_t)t * 16 * K_DIM + kc * 32;
            const float4 lo = *(const float4*)(ap);
            const float4 hi = *(const float4*)(ap + 4);
            x2p[t] += lo.x * lo.x + lo.y * lo.y + lo.z * lo.z + lo.w * lo.w
                    + hi.x * hi.x + hi.y * hi.y + hi.z * hi.z + hi.w * hi.w;
            union { unsigned int u[4]; s16x8 v; } pk;
            pk.u[0] = f2bf(lo.x) | (f2bf(lo.y) << 16);
            pk.u[1] = f2bf(lo.z) | (f2bf(lo.w) << 16);
            pk.u[2] = f2bf(hi.x) | (f2bf(hi.y) << 16);
            pk.u[3] = f2bf(hi.z) | (f2bf(hi.w) << 16);
            af[t] = pk.v;
            bf[t] = *(const s16x8*)(brow + (size_t)t * 16 * K_DIM + kc * 32);
        }
        // Swapped operands: D = W^T_frag * X_frag -> D row = u, D col = m.
        #pragma unroll
        for (int a = 0; a < 4; ++a)
            #pragma unroll
            for (int b = 0; b < 4; ++b)
                acc[a][b] = __builtin_amdgcn_mfma_f32_16x16x32_bf16(bf[b], af[a], acc[a][b], 0, 0, 0);
    }

    // x2: each lane holds its quad's 32-of-128 k partial for 4 m rows;
    // butterfly across the 4 quads (same col) completes the sum.
    float xs[4];
    #pragma unroll
    for (int t = 0; t < 4; ++t) {
        float s = x2p[t];
        s += __shfl_xor(s, 16);
        s += __shfl_xor(s, 32);
        xs[t] = s;
    }

    float4 ws4[4];
    #pragma unroll
    for (int b = 0; b < 4; ++b) ws4[b] = *(const float4*)&w2[u0 + wn + b * 16 + quad * 4];

    // D layout: matrix-row (u) = quad*4 + r, matrix-col (m) = lane&15.
    #pragma unroll
    for (int a = 0; a < 4; ++a) {
        const size_t mrow = (size_t)(m0 + wm + a * 16 + col) * U_TOT;
        #pragma unroll
        for (int b = 0; b < 4; ++b) {
            const int ub = u0 + wn + b * 16 + quad * 4;
            float4 o;
            o.x = xs[a] + ws4[b].x - 2.0f * acc[a][b][0];
            o.y = xs[a] + ws4[b].y - 2.0f * acc[a][b][1];
            o.z = xs[a] + ws4[b].z - 2.0f * acc[a][b][2];
            o.w = xs[a] + ws4[b].w - 2.0f * acc[a][b][3];
            *(float4*)&out[mrow + ub] = o;
        }
    }
}

// Fallback (workspace too small): correct fp32 path.
__global__ __launch_bounds__(256) void fallback_kernel(
    const float* __restrict__ x, const float* __restrict__ w,
    float* __restrict__ out)
{
    __shared__ float xrow[K_DIM];
    const int m = blockIdx.x;
    const int tid = threadIdx.x;
    if (tid < K_DIM) xrow[tid] = x[(size_t)m * K_DIM + tid];
    __syncthreads();
    float x2 = 0.f;
    #pragma unroll
    for (int k = 0; k < K_DIM; ++k) x2 += xrow[k] * xrow[k];
    #pragma unroll
    for (int uu = 0; uu < 4; ++uu) {
        const int u = uu * 256 + tid;
        float dot = 0.f, w2 = 0.f;
        for (int k = 0; k < K_DIM; ++k) {
            const float wv = w[(size_t)k * U_TOT + u];
            dot += xrow[k] * wv;
            w2 += wv * wv;
        }
        out[(size_t)m * U_TOT + u] = x2 + w2 - 2.0f * dot;
    }
}

extern "C" void kernel_launch(void* const* d_in, const int* in_sizes, int n_in,
                              void* d_out, int out_size, void* d_ws, size_t ws_size,
                              hipStream_t stream) {
    const float* x = (const float*)d_in[0];
    const float* w = (const float*)d_in[1];
    float* out = (float*)d_out;

    // ws layout: wt bf16[1024*128] (256 KiB) | w2 f32[1024] (4 KiB)
    const size_t need = (size_t)U_TOT * K_DIM * 2 + (size_t)U_TOT * 4;
    if (ws_size < need) {
        fallback_kernel<<<M_TOT, 256, 0, stream>>>(x, w, out);
        return;
    }

    unsigned short* wt = (unsigned short*)d_ws;
    float* w2 = (float*)(wt + (size_t)U_TOT * K_DIM);

    prep_w<<<U_TOT / 4, 256, 0, stream>>>(w, (unsigned int*)wt, w2);
    gemm_kernel<<<(M_TOT / 128) * (U_TOT / 128), 256, 0, stream>>>(x, wt, w2, out);
}

// Round 5
// 175.589 us; speedup vs baseline: 1.1086x; 1.1086x over previous
//
#include <hip/hip_runtime.h>

// out[m,u] = x2[m] + w2[u] - 2 * sum_k x[m,k] * w[k,u]
// x[8*4096, 128] f32, w[128, 1024] f32, out[32768, 1024] f32
#define M_TOT 32768
#define K_DIM 128
#define U_TOT 1024
#define LDS_STRIDE 136   // 128 + 8: 16B-aligned rows, +4-bank rotation per row

typedef short s16x8 __attribute__((ext_vector_type(8)));   // 8 bf16 as shorts
typedef float f32x4 __attribute__((ext_vector_type(4)));

// round-to-nearest-even fp32 -> bf16 (as ushort)
__device__ inline unsigned int f2bf(float f) {
    union { float f; unsigned int u; } v; v.f = f;
    unsigned int r = v.u + 0x7FFFu + ((v.u >> 16) & 1u);
    return r >> 16;
}

// Tiny prep: w[128,1024] -> w^T bf16 (u-major rows, k contiguous) + w2[u].
__global__ __launch_bounds__(256) void prep_w(
    const float* __restrict__ w, unsigned int* __restrict__ wt, float* __restrict__ w2)
{
    const int lane = threadIdx.x & 63;
    const int u = (blockIdx.x << 2) + (threadIdx.x >> 6);
    const float a = w[(size_t)(2 * lane) * U_TOT + u];
    const float b = w[(size_t)(2 * lane + 1) * U_TOT + u];
    float s = a * a + b * b;
    #pragma unroll
    for (int off = 32; off; off >>= 1) s += __shfl_xor(s, off);
    wt[u * 64 + lane] = f2bf(a) | (f2bf(b) << 16);
    if (lane == 0) w2[u] = s;
}

// GEMM: burst-stage x-tile fp32->bf16 into LDS once (fused x2), then a
// barrier-free 4-chunk MFMA loop from LDS (A) + L2-resident wt (B).
// Swizzle: m_tile = blockIdx&255, u_tile = blockIdx>>8 -> all 8 u-tiles of an
// m-tile land on the SAME XCD (stride 256 == 0 mod 8), so x is L2-re-served.
// Transposed MFMA accumulate (D row = u) -> float4 stores along u.
__global__ __launch_bounds__(256) void gemm_kernel(
    const float* __restrict__ x, const unsigned short* __restrict__ wt,
    const float* __restrict__ w2, float* __restrict__ out)
{
    __shared__ __align__(16) unsigned short xs_lds[128 * LDS_STRIDE];
    __shared__ float x2row[128];

    const int tid = threadIdx.x;
    const int m0 = (int)(blockIdx.x & 255) * 128;
    const int u0 = (int)(blockIdx.x >> 8) * 128;

    // ---- Stage x-tile: 2 threads/row, 64 floats (16 dwordx4) each ----
    {
        const int row = tid >> 1;
        const int half = tid & 1;
        const float4* xp = (const float4*)(x + (size_t)(m0 + row) * K_DIM + half * 64);
        unsigned short* lp = &xs_lds[row * LDS_STRIDE + half * 64];
        float4 v[16];
        #pragma unroll
        for (int i = 0; i < 16; ++i) v[i] = xp[i];
        float s = 0.f;
        #pragma unroll
        for (int i = 0; i < 16; ++i)
            s += v[i].x * v[i].x + v[i].y * v[i].y + v[i].z * v[i].z + v[i].w * v[i].w;
        #pragma unroll
        for (int i = 0; i < 16; i += 2) {
            union { unsigned int u[4]; s16x8 q; } pk;
            pk.u[0] = f2bf(v[i].x)     | (f2bf(v[i].y) << 16);
            pk.u[1] = f2bf(v[i].z)     | (f2bf(v[i].w) << 16);
            pk.u[2] = f2bf(v[i + 1].x) | (f2bf(v[i + 1].y) << 16);
            pk.u[3] = f2bf(v[i + 1].z) | (f2bf(v[i + 1].w) << 16);
            *(s16x8*)&lp[i * 4] = pk.q;
        }
        s += __shfl_xor(s, 1);            // combine the two halves of the row
        if (half == 0) x2row[row] = s;
    }
    __syncthreads();                      // single barrier in the kernel

    // ---- MFMA main loop ----
    const int wv = tid >> 6;
    const int lane = tid & 63;
    const int col = lane & 15;
    const int quad = lane >> 4;
    const int wm = (wv & 1) * 64;
    const int wn = (wv >> 1) * 64;
    const unsigned short* brow = wt + (size_t)(u0 + wn + col) * K_DIM + quad * 8;

    f32x4 acc[4][4] = {};                 // acc[a][b]: m-subtile a, u-subtile b
    #pragma unroll
    for (int kc = 0; kc < 4; ++kc) {
        s16x8 af[4], bf[4];
        #pragma unroll
        for (int t = 0; t < 4; ++t) {
            af[t] = *(const s16x8*)&xs_lds[(wm + t * 16 + col) * LDS_STRIDE + kc * 32 + quad * 8];
            bf[t] = *(const s16x8*)(brow + (size_t)t * 16 * K_DIM + kc * 32);
        }
        // Swapped operands: D = W^T_frag * X_frag -> D row = u, D col = m.
        #pragma unroll
        for (int a = 0; a < 4; ++a)
            #pragma unroll
            for (int b = 0; b < 4; ++b)
                acc[a][b] = __builtin_amdgcn_mfma_f32_16x16x32_bf16(bf[b], af[a], acc[a][b], 0, 0, 0);
    }

    // ---- Epilogue: D row (u) = quad*4 + r, D col (m) = lane&15 ----
    float xs[4];
    #pragma unroll
    for (int a = 0; a < 4; ++a) xs[a] = x2row[wm + a * 16 + col];
    float4 ws4[4];
    #pragma unroll
    for (int b = 0; b < 4; ++b) ws4[b] = *(const float4*)&w2[u0 + wn + b * 16 + quad * 4];

    #pragma unroll
    for (int a = 0; a < 4; ++a) {
        const size_t mrow = (size_t)(m0 + wm + a * 16 + col) * U_TOT;
        #pragma unroll
        for (int b = 0; b < 4; ++b) {
            const int ub = u0 + wn + b * 16 + quad * 4;
            float4 o;
            o.x = xs[a] + ws4[b].x - 2.0f * acc[a][b][0];
            o.y = xs[a] + ws4[b].y - 2.0f * acc[a][b][1];
            o.z = xs[a] + ws4[b].z - 2.0f * acc[a][b][2];
            o.w = xs[a] + ws4[b].w - 2.0f * acc[a][b][3];
            *(float4*)&out[mrow + ub] = o;
        }
    }
}

// Fallback (workspace too small): correct fp32 path.
__global__ __launch_bounds__(256) void fallback_kernel(
    const float* __restrict__ x, const float* __restrict__ w,
    float* __restrict__ out)
{
    __shared__ float xrow[K_DIM];
    const int m = blockIdx.x;
    const int tid = threadIdx.x;
    if (tid < K_DIM) xrow[tid] = x[(size_t)m * K_DIM + tid];
    __syncthreads();
    float x2 = 0.f;
    #pragma unroll
    for (int k = 0; k < K_DIM; ++k) x2 += xrow[k] * xrow[k];
    #pragma unroll
    for (int uu = 0; uu < 4; ++uu) {
        const int u = uu * 256 + tid;
        float dot = 0.f, w2 = 0.f;
        for (int k = 0; k < K_DIM; ++k) {
            const float wv = w[(size_t)k * U_TOT + u];
            dot += xrow[k] * wv;
            w2 += wv * wv;
        }
        out[(size_t)m * U_TOT + u] = x2 + w2 - 2.0f * dot;
    }
}

extern "C" void kernel_launch(void* const* d_in, const int* in_sizes, int n_in,
                              void* d_out, int out_size, void* d_ws, size_t ws_size,
                              hipStream_t stream) {
    const float* x = (const float*)d_in[0];
    const float* w = (const float*)d_in[1];
    float* out = (float*)d_out;

    // ws layout: wt bf16[1024*128] (256 KiB) | w2 f32[1024] (4 KiB)
    const size_t need = (size_t)U_TOT * K_DIM * 2 + (size_t)U_TOT * 4;
    if (ws_size < need) {
        fallback_kernel<<<M_TOT, 256, 0, stream>>>(x, w, out);
        return;
    }

    unsigned short* wt = (unsigned short*)d_ws;
    float* w2 = (float*)(wt + (size_t)U_TOT * K_DIM);

    prep_w<<<U_TOT / 4, 256, 0, stream>>>(w, (unsigned int*)wt, w2);
    gemm_kernel<<<(M_TOT / 128) * (U_TOT / 128), 256, 0, stream>>>(x, wt, w2, out);
}